// Round 10
// baseline (260.730 us; speedup 1.0000x reference)
//
#include <hip/hip_runtime.h>

#define BATCH   16384
#define NUM_NUM 32
#define NUM_CAT 32
#define CARD    128
#define OUT_F   32
#define XSTRIDE 4128   // NUM_NUM + NUM_CAT*CARD
#define OSTRIDE 1056   // NUM_NUM + NUM_CAT*OUT_F

#define TRB 64    // rows per block (one stripe)
#define NIT 16    // items per block = feature-pairs
#define QPB (TRB * 64)  // 4096 quads per x buffer (64 rows x 256 floats) = 64 KB

typedef const __attribute__((address_space(1))) void* as1_cvp;
typedef __attribute__((address_space(3))) void*       as3_vp;

// Persistent-stripe pipeline: block = 64-row stripe, iterates 16 feature-PAIRS
// (f,f+1 adjacent in x -> 1024B contiguous per staged row). 512 thr = 8 waves;
// wave = (fsel = wv>>2, og = wv&3); lane = row. W + bias via wave-uniform s_load
// (SMEM pipe). x_s swizzle: logical Q = row*64 + (fsel*32+c4), phys = Q^((Q>>6)&7)
// = row*64 + (col ^ (row&7)) -> involution; read & stage both 2-way max.
// Counted-vmcnt pipeline (T3/T4): stage(it+2) issued mid-iter; waits are
// s_waitcnt vmcnt(8) (next item's 8 loads may remain; op ledger: pass(2) oldest,
// 8 loads/item, 2 stores/iter -> steady newer-than-stage(it) = 12 >= 8 safe;
// final iter newer = 4 -> vmcnt(4)). Raw s_barrier everywhere: vmcnt NEVER
// drains to 0 in the loop -> HBM streams through compute and barriers.
// LDS 2x64KB + 16KB ctr = 144KB -> 1 block/CU, 256 blocks exact.
__global__ __launch_bounds__(512, 1) void emb_pipe(const float* __restrict__ x,
                                                   const float* __restrict__ Wm,
                                                   const float* __restrict__ bias,
                                                   float* __restrict__ out) {
    __shared__ float4 x_s[2][QPB];    // 128 KB
    __shared__ float4 ctr[TRB * 16];  // 16 KB transpose buffer

    const int row0 = blockIdx.x * TRB;
    const int tid  = threadIdx.x;
    const int l    = tid & 63;
    const int lx   = l & 7;
    const int wv   = __builtin_amdgcn_readfirstlane(tid >> 6);  // 0..7
    const int fsel = wv >> 2;  // which feature of the pair
    const int og   = wv & 3;   // out-group of 8

    // ---- numeric passthrough (oldest vm ops: 1 load + 1 store per thread) ----
    {
        const int r  = tid >> 3;
        const int c4 = (tid & 7) << 2;
        *(float4*)(out + (size_t)(row0 + r) * OSTRIDE + c4) =
            *(const float4*)(x + (size_t)(row0 + r) * XSTRIDE + c4);
    }

    const float* xbase = x + (size_t)row0 * XSTRIDE + NUM_NUM;

    // stage item -> buf: 64 instrs (8/wave), instr i stages row i's 1024B slice,
    // lanes XOR-permuted within 128B groups (inverse swizzle; coalescing intact).
    auto stage = [&](int item, int buf) {
        const float* src0 = xbase + item * (2 * CARD);
#pragma unroll
        for (int s = 0; s < 8; ++s) {
            const int i = wv * 8 + s;  // row 0..63
            __builtin_amdgcn_global_load_lds(
                (as1_cvp)(src0 + (size_t)i * XSTRIDE + ((l ^ (i & 7)) << 2)),
                (as3_vp)&x_s[buf][i * 64 + l], 16, 0, 0);
        }
    };

    stage(0, 0);
    stage(1, 1);

    for (int it = 0; it < NIT; ++it) {
        // W1: wait for item it's loads (never drain to 0), then barrier.
        if (it < NIT - 1) { asm volatile("s_waitcnt vmcnt(8)" ::: "memory"); }
        else              { asm volatile("s_waitcnt vmcnt(4)" ::: "memory"); }
        __builtin_amdgcn_s_barrier();
        __builtin_amdgcn_sched_barrier(0);

        const float4* xb  = x_s[it & 1];
        const float4* wqn = (const float4*)Wm +
                            ((size_t)(it * 2 + fsel) * (CARD * OUT_F / 4) + og * 2);

        float acc[8];
#pragma unroll
        for (int k = 0; k < 8; ++k) acc[k] = 0.0f;

#pragma unroll 4
        for (int c4 = 0; c4 < 32; ++c4) {
            const float4 xv = xb[l * 64 + fsel * 32 + (c4 ^ lx)];
#pragma unroll
            for (int cc = 0; cc < 4; ++cc) {
                const int    c  = c4 * 4 + cc;
                const float4 wa = wqn[c * 8];      // s_load_dwordx4 (wave-uniform)
                const float4 wb = wqn[c * 8 + 1];
                const float  xf = (&xv.x)[cc];
                acc[0] += xf * wa.x;  acc[1] += xf * wa.y;
                acc[2] += xf * wa.z;  acc[3] += xf * wa.w;
                acc[4] += xf * wb.x;  acc[5] += xf * wb.y;
                acc[6] += xf * wb.z;  acc[7] += xf * wb.w;
            }
        }

        // B2: all reads of buf[it&1] done -> safe to restage it.
        __builtin_amdgcn_s_barrier();
        __builtin_amdgcn_sched_barrier(0);
        if (it + 2 < NIT) stage(it + 2, it & 1);

        // bias (wave-uniform scalar) + transpose-write to ctr (swizzled, 2-way).
        const float4* bq = (const float4*)bias + ((it * 2 + fsel) * 8 + og * 2);
        const float4  b0 = bq[0];
        const float4  b1 = bq[1];
        const int     cq0 = fsel * 8 + og * 2;
        ctr[l * 16 + (cq0 ^ lx)] =
            make_float4(acc[0] + b0.x, acc[1] + b0.y, acc[2] + b0.z, acc[3] + b0.w);
        ctr[l * 16 + ((cq0 + 1) ^ lx)] =
            make_float4(acc[4] + b1.x, acc[5] + b1.y, acc[6] + b1.z, acc[7] + b1.w);

        // B3: LDS writes visible (lgkm only — vmcnt untouched).
        asm volatile("s_waitcnt lgkmcnt(0)" ::: "memory");
        __builtin_amdgcn_s_barrier();
        __builtin_amdgcn_sched_barrier(0);

        // coalesced stores: 8 lanes x 2 quads cover one row's 256B for this pair.
        const int    rr = tid >> 3;
        const int    qp = (tid & 7) * 2;
        const float4 v0 = ctr[rr * 16 + (qp ^ (rr & 7))];
        const float4 v1 = ctr[rr * 16 + ((qp + 1) ^ (rr & 7))];
        float* orow = out + (size_t)(row0 + rr) * OSTRIDE + NUM_NUM + it * 64 + qp * 4;
        *(float4*)(orow)     = v0;
        *(float4*)(orow + 4) = v1;
    }
}

extern "C" void kernel_launch(void* const* d_in, const int* in_sizes, int n_in,
                              void* d_out, int out_size, void* d_ws, size_t ws_size,
                              hipStream_t stream) {
    const float* x    = (const float*)d_in[0];
    const float* W    = (const float*)d_in[1];
    const float* bias = (const float*)d_in[2];
    float*       out  = (float*)d_out;

    emb_pipe<<<BATCH / TRB / 1, 512, 0, stream>>>(x, W, bias, out);  // 256 blocks, 1/CU
}

// Round 11
// 87.496 us; speedup vs baseline: 2.9799x; 2.9799x over previous
//
#include <hip/hip_runtime.h>

#define BATCH   16384
#define NUM_NUM 32
#define NUM_CAT 32
#define CARD    128
#define OUT_F   32
#define XSTRIDE 4128   // NUM_NUM + NUM_CAT*CARD
#define OSTRIDE 1056   // NUM_NUM + NUM_CAT*OUT_F

#define TRB    64              // rows per block
#define CK     32              // K cols per chunk
#define NCHUNK (CARD / CK)     // 4
#define QPB    (TRB * CK / 4)  // 512 quads per buffer (8 KB)

typedef const __attribute__((address_space(1))) void* as1_cvp;
typedef __attribute__((address_space(3))) void*       as3_vp;

// 256 thr = 4 waves, 6 blocks/CU (16 KB LDS, VGPR-capped 85). Wave og owns outs
// [og*8,+8) -> W + bias wave-uniform s_load (SMEM pipe, off LDS). Lane = row.
// Dbuf with the ORDER FIX vs r7: per iter [compute k][sync][stage k+2] -> the
// stage drained by each sync was issued one full compute earlier (hidden), and
// stage(k+2)'s target buf[k&1] is barrier-separated from its compute(k) readers.
// x_s swizzle: logical Q = row*8 + c4, phys = Q ^ ((Q>>3)&7) (involution).
//   read (fixed c4): addr = l*8 + (c4^(l&7)) -> ~1.33x bank cost (accepted, r7/r10).
//   stage instr i (=og*2+s): lane l -> row i*8+(l>>3), cq (l&7)^((l>>3)&7):
//   8-lane groups cover one row's 128B slice permuted -> coalesced segments.
// Epilogue ctr (64x8 quads, 8 KB) overlaid on buf0 (dead after compute(2)+sync).
__global__ __launch_bounds__(256, 6) void emb_gemv(const float* __restrict__ x,
                                                   const float* __restrict__ Wm,
                                                   const float* __restrict__ bias,
                                                   float* __restrict__ out) {
    __shared__ float4 lds[2 * QPB];  // 16 KB: buf0 = [0,512), buf1 = [512,1024); ctr = buf0

    const int f    = blockIdx.x;
    const int row0 = blockIdx.y * TRB;
    const int tid  = threadIdx.x;
    const int l    = tid & 63;
    const int lx   = l & 7;
    const int og   = __builtin_amdgcn_readfirstlane(tid >> 6);  // wave out-group

    const float* xg   = x + (size_t)row0 * XSTRIDE + NUM_NUM + f * CARD;
    const int    srow = l >> 3;                    // stage: row-within-8
    const int    scq  = (l & 7) ^ ((l >> 3) & 7);  // stage: inverse-swizzled col-quad

    // stage chunk ck -> buffer buf: 8 gload_lds block-wide (2 per wave)
    auto stage = [&](int ck, int buf) {
#pragma unroll
        for (int s = 0; s < 2; ++s) {
            const int i = og * 2 + s;  // instr 0..7, covers phys quads [i*64, i*64+64)
            __builtin_amdgcn_global_load_lds(
                (as1_cvp)(xg + (size_t)(i * 8 + srow) * XSTRIDE + ck * CK + scq * 4),
                (as3_vp)&lds[buf * QPB + i * 64 + l], 16, 0, 0);
        }
    };

    stage(0, 0);
    stage(1, 1);

    // wave-uniform W quad pointer: wq[c*8], wq[c*8+1] = W[f][c][og*8 .. +8)
    const float4* __restrict__ wq =
        (const float4*)Wm + ((size_t)f * (CARD * OUT_F / 4) + og * 2);

    float acc[8];
#pragma unroll
    for (int k = 0; k < 8; ++k) acc[k] = 0.0f;

    __syncthreads();  // publishes chunks 0,1 (cold-start drain, once per block)

    for (int ck = 0; ck < NCHUNK; ++ck) {
        const float4* xb = &lds[(ck & 1) * QPB];

        float4 xv[8];
#pragma unroll
        for (int c4 = 0; c4 < 8; ++c4) xv[c4] = xb[l * 8 + (c4 ^ lx)];

#pragma unroll
        for (int c4 = 0; c4 < 8; ++c4) {
#pragma unroll
            for (int cc = 0; cc < 4; ++cc) {
                const int    c  = ck * CK + c4 * 4 + cc;
                const float4 wa = wq[c * 8];      // s_load_dwordx4 (uniform)
                const float4 wb = wq[c * 8 + 1];
                const float  xf = (&xv[c4].x)[cc];
                acc[0] += xf * wa.x;  acc[1] += xf * wa.y;
                acc[2] += xf * wa.z;  acc[3] += xf * wa.w;
                acc[4] += xf * wb.x;  acc[5] += xf * wb.y;
                acc[6] += xf * wb.z;  acc[7] += xf * wb.w;
            }
        }

        if (ck < NCHUNK - 1) {
            __syncthreads();                       // publishes stage(ck+1) [issued one
            if (ck + 2 < NCHUNK) stage(ck + 2, ck & 1);  //  compute earlier]; frees buf
        }
    }

    // ---- epilogue: bias (uniform) + transpose through ctr (= buf0, dead region) ----
    const float4 b0 = ((const float4*)bias)[f * 8 + og * 2];
    const float4 b1 = ((const float4*)bias)[f * 8 + og * 2 + 1];
    lds[l * 8 + ((og * 2) ^ lx)] =
        make_float4(acc[0] + b0.x, acc[1] + b0.y, acc[2] + b0.z, acc[3] + b0.w);
    lds[l * 8 + ((og * 2 + 1) ^ lx)] =
        make_float4(acc[4] + b1.x, acc[5] + b1.y, acc[6] + b1.z, acc[7] + b1.w);
    __syncthreads();

    // coalesced stores: 4 threads cover one row's 128B
    {
        const int    r  = tid >> 2;
        const int    qp = (tid & 3) * 2;
        const float4 v0 = lds[r * 8 + (qp ^ (r & 7))];
        const float4 v1 = lds[r * 8 + ((qp + 1) ^ (r & 7))];
        float* orow = out + (size_t)(row0 + r) * OSTRIDE + NUM_NUM + f * OUT_F + qp * 4;
        *(float4*)(orow)     = v0;
        *(float4*)(orow + 4) = v1;
    }

    // ---- numeric passthrough: f==0 blocks copy their stripe's first 32 cols ----
    if (f == 0) {
#pragma unroll
        for (int it = 0; it < 2; ++it) {
            const int idx = it * 256 + tid;  // 512 float4
            const int r   = idx >> 3;
            const int c4  = (idx & 7) << 2;
            *(float4*)(out + (size_t)(row0 + r) * OSTRIDE + c4) =
                *(const float4*)(x + (size_t)(row0 + r) * XSTRIDE + c4);
        }
    }
}

extern "C" void kernel_launch(void* const* d_in, const int* in_sizes, int n_in,
                              void* d_out, int out_size, void* d_ws, size_t ws_size,
                              hipStream_t stream) {
    const float* x    = (const float*)d_in[0];
    const float* W    = (const float*)d_in[1];
    const float* bias = (const float*)d_in[2];
    float*       out  = (float*)d_out;

    dim3 grid(NUM_CAT, BATCH / TRB);  // (32, 256), f fastest
    emb_gemv<<<grid, 256, 0, stream>>>(x, W, bias, out);
}